// Round 13
// baseline (289.886 us; speedup 1.0000x reference)
//
#include <hip/hip_runtime.h>

typedef float f32x4  __attribute__((ext_vector_type(4)));
typedef float f32x16 __attribute__((ext_vector_type(16)));
typedef int   i32x4  __attribute__((ext_vector_type(4)));
typedef int   i32x8  __attribute__((ext_vector_type(8)));

#define AS1 __attribute__((address_space(1)))
#define AS3 __attribute__((address_space(3)))

// ---------------------------------------------------------------------------
// Kernel 1 (R1, proven): per-token quant of x -> fp8 e4m3 + scale
// ---------------------------------------------------------------------------
__global__ __launch_bounds__(256) void quant_x_fp8_kernel(
    const float* __restrict__ x, unsigned char* __restrict__ x8,
    float* __restrict__ xs, int K) {
  int m = blockIdx.x;
  int t = threadIdx.x;
  const f32x4* src = (const f32x4*)(x + (size_t)m * K + t * 16);
  f32x4 v[4];
  float am = 0.0f;
#pragma unroll
  for (int i = 0; i < 4; ++i) {
    v[i] = src[i];
#pragma unroll
    for (int j = 0; j < 4; ++j) am = fmaxf(am, __builtin_fabsf(v[i][j]));
  }
#pragma unroll
  for (int off = 32; off >= 1; off >>= 1)
    am = fmaxf(am, __shfl_xor(am, off, 64));
  __shared__ float red[4];
  int wv = t >> 6, lane = t & 63;
  if (lane == 0) red[wv] = am;
  __syncthreads();
  am = fmaxf(fmaxf(red[0], red[1]), fmaxf(red[2], red[3]));
  am = fmaxf(am, 1e-12f);
  float sc = am / 448.0f;
  if (t == 0) xs[m] = sc;
  i32x4 out;
#pragma unroll
  for (int i = 0; i < 4; ++i) {
    float q0 = v[i][0] / sc, q1 = v[i][1] / sc;
    float q2 = v[i][2] / sc, q3 = v[i][3] / sc;
    int p = __builtin_amdgcn_cvt_pk_fp8_f32(q0, q1, 0, false);
    p = __builtin_amdgcn_cvt_pk_fp8_f32(q2, q3, p, true);
    out[i] = p;
  }
  *(i32x4*)(x8 + (size_t)m * K + t * 16) = out;
}

// ---------------------------------------------------------------------------
// Kernel 2 (R1, proven): weight f32 (fp8-representable) -> fp8 bytes
// ---------------------------------------------------------------------------
__global__ __launch_bounds__(256) void quant_w_fp8_kernel(
    const float* __restrict__ w, unsigned char* __restrict__ w8) {
  size_t idx = (size_t)blockIdx.x * 256 + threadIdx.x;
  const f32x4* src = (const f32x4*)w + idx * 4;
  i32x4 out;
#pragma unroll
  for (int i = 0; i < 4; ++i) {
    f32x4 v = src[i];
    int p = __builtin_amdgcn_cvt_pk_fp8_f32(v[0], v[1], 0, false);
    p = __builtin_amdgcn_cvt_pk_fp8_f32(v[2], v[3], p, true);
    out[i] = p;
  }
  ((i32x4*)w8)[idx] = out;
}

// ---------------------------------------------------------------------------
// Kernel 3: MX-fp8 GEMM. R25 = 128x64 wave tile (R24, -25% LDS/FLOP, 212
// VGPR no-spill) x 2 co-resident blocks (R23 mechanism) via K-64 buffers.
// Resource model (R23+R24): LDS service is PER-CU. Per 8.4 MFLOP: 64x64
// wave tiles need 128 b128 reads (1536cy) + ~500 stage writes = ~2100cy
// vs MFMA 1100 -> LDS-port-bound (R23 measured 68% port busy). 128x64
// tiles need 96 reads (~1730cy floor) but R24's 1-block/4-wave had no
// TLP. R25: 256 thr, block 256x128, wave 128x64, K-step 64 bodies ->
// buf = A 16KB + B 8KB = 24KB; 3 bufs = 73728 -> 2 blocks/CU (147456 <=
// 163840, 16KB slack; VGPR 212x8 = 1696 <= 2048). Counted vmcnt(6),
// 1 barrier/body, stage body T+2 during T (R17 WAR rule: S(T+2) hits buf
// (T-1)%3, reads retired before barrier(T-1)).
// K-64 layout: rows are 64B; packed 2 rows per 128B line. Logical (row r,
// 16B-slot s in 0..3) -> line r>>1, slot8 = ((r&1)<<2 | s) ^ ((r>>1)&7)
// (same XOR-involution family as the validated K-128 swizzle). Staging
// inverse (linear dest tid*16): inv = (tid&7)^((tid>>3)&7); src row =
// 64*sweep + 2*(tid>>3) + (inv>>2), col = (inv&3)*16. Read anchors: lane
// (l31,hi2) reads slots {2hi2, 2hi2+1} of row Rbase+l31: anchor(s) =
// (l31>>1)*128 + ((((l31&1)<<2)|s) ^ ((l31>>1)&7))*16; Rbase multiples of
// 32 shift by Rbase*64 bytes (swizzle invariant since 16 = 0 mod 8).
// Fragment bytes per lane identical to validated K-128 frags (slots
// {2hi2,2hi2+1} = bytes 32*hi2..+32 of the K-64 chunk).
// Scale block = K-128 = 2 bodies: ratio-fold (R20-validated) applied on
// EVEN bodies only (acc *= s_prev/s_cur then chain); odd bodies chain
// directly. Epilogue * s_last (R24-proven mapping for wave 128x64).
// vmcnt ledger: 6 gloads/body (A 4 + B 2). Prologue S0,S1 -> vmcnt(6)
// retires S0, leaves 6. Body b issues S(b+2) (->12); end vmcnt(6)
// retires S(b+1). Tail bodies 62,63: no stage, vmcnt(0).
// Tripwires: Occupancy ~22-25 (11 => no co-residency); WRITE == 131072KB;
// VGPR ~190-215; LDS_Block 73728.
// ---------------------------------------------------------------------------
__global__ __launch_bounds__(256, 1) void gemm_mxfp8_kernel(
    const unsigned char* __restrict__ A8,   // [M][K] fp8
    const unsigned char* __restrict__ W8,   // [N][K] fp8
    const float* __restrict__ xs,           // [M]
    const float* __restrict__ wsinv,        // [N/128][K/128]
    float* __restrict__ Y,                  // [M][N] f32
    int M, int N, int K) {
  const int KB = K >> 7;  // K/128 scale tiles (32); bodies = 2*KB

  int bid = blockIdx.x, nwg = gridDim.x;
  int wg = (bid & 7) * (nwg >> 3) + (bid >> 3);
  int mt = M >> 8;                  // 16
  int bm = wg & (mt - 1);
  int bn = wg / mt;                 // 0..63
  int m0 = bm << 8, n0 = bn << 7;   // 256 x 128 tile

  __shared__ __align__(16) char lds[73728];  // 3 bufs x 24576 (A 16K, B 8K)

  const int tid = threadIdx.x, wv = tid >> 6, lane = tid & 63;
  const int wr = wv >> 1, wc = wv & 1;          // 2 x 2 wave grid
  const int l31 = lane & 31, hi2 = lane >> 5;

  // read anchors for the K-64 interleaved layout:
  // anchor(s) = (l31>>1)*128 + ((((l31&1)<<2)|s) ^ ((l31>>1)&7))*16
  const int lineB = (l31 >> 1) * 128;
  const int par4 = (l31 & 1) << 2;
  const int xr = (l31 >> 1) & 7;
  const int s0 = 2 * hi2, s1 = 2 * hi2 + 1;
  const int aL = wr * 8192 + lineB + ((par4 | s0) ^ xr) * 16;
  const int aH = wr * 8192 + lineB + ((par4 | s1) ^ xr) * 16;
  const int bL = wc * 4096 + lineB + ((par4 | s0) ^ xr) * 16;
  const int bH = wc * 4096 + lineB + ((par4 | s1) ^ xr) * 16;

  // staging: dest = region + sweep*4096 + tid*16 (linear);
  // src row = 64*sweep + 2*(tid>>3) + (inv>>2), col = (inv&3)*16.
  const int stgD = tid << 4;
  const int inv = (tid & 7) ^ ((tid >> 3) & 7);
  const int rLoc = 2 * (tid >> 3) + (inv >> 2);
  const int cSrc = (inv & 3) << 4;
  const size_t rowB = (size_t)K;  // fp8: 1 byte/elem
  const size_t g64r = 64 * rowB;  // 64-row sweep stride
  const char* pA = (const char*)A8 + (size_t)(m0 + rLoc) * rowB + cSrc;
  const char* pB = (const char*)W8 + (size_t)(n0 + rLoc) * rowB + cSrc;

  const float* wsv = wsinv + (size_t)bn * KB;  // N-tile 128 = one scale row

  f32x16 acc[4][2];
#pragma unroll
  for (int i = 0; i < 4; ++i)
#pragma unroll
    for (int j = 0; j < 2; ++j) acc[i][j] = (f32x16)0.0f;

  i32x8 af, bf[2];

#define GL(SRC, DST)                                                           \
  __builtin_amdgcn_global_load_lds((const AS1 void*)(SRC), (AS3 void*)(DST),   \
                                   16, 0, 0)
// A panel (256 rows x 64B = 16KB): 4 sweeps
#define STG_A(COND, SB, SRC)                                                   \
  if (COND) {                                                                  \
    const char* s_ = (SRC);                                                    \
    char* d_ = lds + (SB) + stgD;                                              \
    GL(s_, d_);                                                                \
    GL(s_ + g64r, d_ + 4096);                                                  \
    GL(s_ + 2 * g64r, d_ + 8192);                                              \
    GL(s_ + 3 * g64r, d_ + 12288);                                             \
  }
// B panel (128 rows x 64B = 8KB) at region +16384: 2 sweeps
#define STG_B(COND, SB, SRC)                                                   \
  if (COND) {                                                                  \
    const char* s_ = (SRC);                                                    \
    char* d_ = lds + (SB) + 16384 + stgD;                                      \
    GL(s_, d_);                                                                \
    GL(s_ + g64r, d_ + 4096);                                                  \
  }

// A frag for one mj (K-64): 2 ds_read_b128 -> af
#define RD_A(RB, MJ)                                                           \
  {                                                                            \
    const char* p_ = lds + (RB) + (MJ) * 2048;                                 \
    i32x4 lo = *(const i32x4*)(p_ + aL);                                       \
    i32x4 hi = *(const i32x4*)(p_ + aH);                                       \
    af = __builtin_shufflevector(lo, hi, 0, 1, 2, 3, 4, 5, 6, 7);              \
  }
// B frag for one nj (K-64), region +16384: 2 ds_read_b128
#define RD_B(RB, NJ)                                                           \
  {                                                                            \
    const char* p_ = lds + (RB) + 16384 + (NJ) * 2048;                         \
    i32x4 lo = *(const i32x4*)(p_ + bL);                                       \
    i32x4 hi = *(const i32x4*)(p_ + bH);                                       \
    bf[NJ] = __builtin_shufflevector(lo, hi, 0, 1, 2, 3, 4, 5, 6, 7);          \
  }

// fold + MFMA (even bodies): acc = mfma(af, bf, acc*r)
#define MMFF(MJ, NJ, R_)                                                       \
  {                                                                            \
    _Pragma("unroll") for (int q = 0; q < 16; ++q)                             \
        acc[MJ][NJ][q] *= (R_);                                                \
    acc[MJ][NJ] = __builtin_amdgcn_mfma_scale_f32_32x32x64_f8f6f4(             \
        af, bf[NJ], acc[MJ][NJ], 0, 0, 0, 0x7f7f7f7f, 0, 0x7f7f7f7f);          \
  }
// direct MFMA (odd bodies): acc = mfma(af, bf, acc)
#define MMFD(MJ, NJ)                                                           \
  acc[MJ][NJ] = __builtin_amdgcn_mfma_scale_f32_32x32x64_f8f6f4(               \
      af, bf[NJ], acc[MJ][NJ], 0, 0, 0, 0x7f7f7f7f, 0, 0x7f7f7f7f);

#define BODY_CORE(MM0, MM1, MM2, MM3, G, VM)                                   \
  {                                                                            \
    RD_B(rdT, 0);                                                              \
    RD_B(rdT, 1);                                                              \
    RD_A(rdT, 0);                                                              \
    __builtin_amdgcn_s_setprio(1);                                             \
    MM0;                                                                       \
    __builtin_amdgcn_s_setprio(0);                                             \
    STG_A(G, stT, pAs);                                                        \
    RD_A(rdT, 1);                                                              \
    __builtin_amdgcn_s_setprio(1);                                             \
    MM1;                                                                       \
    __builtin_amdgcn_s_setprio(0);                                             \
    STG_B(G, stT, pBs);                                                        \
    RD_A(rdT, 2);                                                              \
    __builtin_amdgcn_s_setprio(1);                                             \
    MM2;                                                                       \
    __builtin_amdgcn_s_setprio(0);                                             \
    RD_A(rdT, 3);                                                              \
    __builtin_amdgcn_s_setprio(1);                                             \
    MM3;                                                                       \
    __builtin_amdgcn_s_setprio(0);                                             \
    asm volatile("s_waitcnt " VM ::: "memory");                                \
    __builtin_amdgcn_s_barrier();                                              \
    rdT = (rdT == 49152) ? 0 : rdT + 24576;                                    \
    stT = (stT == 49152) ? 0 : stT + 24576;                                    \
    pAs += 64;                                                                 \
    pBs += 64;                                                                 \
  }

#define BODY_E(T, G, VM)                                                       \
  {                                                                            \
    float sc_ = wsv[(T)];                                                      \
    float r_ = sp_ / sc_;                                                      \
    sp_ = sc_;                                                                 \
    BODY_CORE(MMFF(0, 0, r_); MMFF(0, 1, r_), MMFF(1, 0, r_); MMFF(1, 1, r_),  \
              MMFF(2, 0, r_); MMFF(2, 1, r_), MMFF(3, 0, r_); MMFF(3, 1, r_),  \
              G, VM)                                                           \
  }
#define BODY_O(G, VM)                                                          \
  BODY_CORE(MMFD(0, 0); MMFD(0, 1), MMFD(1, 0); MMFD(1, 1),                    \
            MMFD(2, 0); MMFD(2, 1), MMFD(3, 0); MMFD(3, 1), G, VM)

  // prologue: body0 -> buf0, body1 -> buf1 (6 gloads each);
  // vmcnt(6) retires body0's, leaves body1's 6 = steady invariant.
  STG_A(true, 0, pA);
  STG_B(true, 0, pB);
  STG_A(true, 24576, pA + 64);
  STG_B(true, 24576, pB + 64);
  asm volatile("s_waitcnt vmcnt(6)" ::: "memory");
  __builtin_amdgcn_s_barrier();

  int rdT = 0, stT = 49152;   // read buf of body b; stage buf of body b+2
  const char* pAs = pA + 128;  // stage source K-offset of body 2
  const char* pBs = pB + 128;
  float sp_ = wsv[0];          // previous-tile scale (ratio = 1 at t = 0)

#pragma unroll 1
  for (int t = 0; t < KB - 1; ++t) {
    BODY_E(t, true, "vmcnt(6)")
    BODY_O(true, "vmcnt(6)")
  }
  // tail: bodies 2KB-2, 2KB-1; no staging; drain.
  BODY_E(KB - 1, false, "vmcnt(0)")
  BODY_O(false, "vmcnt(0)")

#undef BODY_O
#undef BODY_E
#undef BODY_CORE
#undef MMFD
#undef MMFF
#undef RD_B
#undef RD_A
#undef STG_B
#undef STG_A
#undef GL

  // epilogue (R24-proven mapping, wave 128x64): col=l31, row=q*8+hi2*4+j.
  // acc is in s_last domain: Y = acc * s_last * xs[row].
  const float sl_ = sp_;
#pragma unroll
  for (int mj = 0; mj < 4; ++mj)
#pragma unroll
    for (int nj = 0; nj < 2; ++nj) {
      int col = n0 + wc * 64 + nj * 32 + l31;
#pragma unroll
      for (int q = 0; q < 4; ++q) {
        int row0 = m0 + wr * 128 + mj * 32 + q * 8 + hi2 * 4;
        f32x4 sv = *(const f32x4*)(xs + row0);
#pragma unroll
        for (int j = 0; j < 4; ++j)
          Y[(size_t)(row0 + j) * N + col] = acc[mj][nj][q * 4 + j] * sv[j] * sl_;
      }
    }
}

// ---------------------------------------------------------------------------
extern "C" void kernel_launch(void* const* d_in, const int* in_sizes, int n_in,
                              void* d_out, int out_size, void* d_ws, size_t ws_size,
                              hipStream_t stream) {
  const float* x     = (const float*)d_in[0];   // [B,S,K] f32
  const float* w     = (const float*)d_in[1];   // [N,K] f32 (fp8-representable)
  const float* wsinv = (const float*)d_in[2];   // [N/128,K/128] f32
  float* y = (float*)d_out;

  const int K = 4096;
  const int M = in_sizes[0] / K;   // 4096
  const int N = in_sizes[1] / K;   // 8192

  unsigned char* x8 = (unsigned char*)d_ws;                       // M*K
  float* xs = (float*)((char*)d_ws + (size_t)M * K);              // M floats
  unsigned char* w8 =
      (unsigned char*)d_ws + (size_t)M * K + (size_t)M * 4;       // N*K

  quant_x_fp8_kernel<<<M, 256, 0, stream>>>(x, x8, xs, K);
  quant_w_fp8_kernel<<<(int)(((size_t)N * K / 16 + 255) / 256), 256, 0,
                       stream>>>(w, w8);

  dim3 grid((M / 256) * (N / 128));  // 1024
  gemm_mxfp8_kernel<<<grid, 256, 0, stream>>>(x8, w8, xs, wsinv, y, M, N, K);
}